// Round 5
// baseline (182.165 us; speedup 1.0000x reference)
//
#include <hip/hip_runtime.h>
#include <math.h>

#define DDIM 128
#define NSEQ 8192
#define SUB 16        // steps per unit in sk_seg
#define SEG 64        // steps per seg block (4 units)
#define NSEGB 128     // 8192/64 -> 128 segment matrices
#define NTRI 45       // lower-triangular entries (L,q), q<=L, L=0..8

#define TRI(L,q) ((L)*((L)+1)/2 + (q))

// ws layout (bytes)
#define OFF_PHAT 0                      // float2 [4][8][128]    = 32768
#define OFF_AB   32768                  // float2 [8192][8]      = 524288
#define OFF_MSEG 557056                 // float2 [128][45][128] = 5898240
#define OFF_MT1  6455296                // float2 [32][45][128]  = 1474560
#define OFF_MT2  7929856                // float2 [8][45][128]   = 368640
// total ~8.3 MB

// ---------------------------------------------------------- reg helpers ----
__device__ __forceinline__ void loadG(const float2* __restrict__ p, int fq,
                                      float (&R)[NTRI], float (&I)[NTRI]) {
#pragma unroll
  for (int e = 0; e < NTRI; ++e) {
    float2 t = p[e*128 + fq];
    R[e] = t.x; I[e] = t.y;
  }
}

__device__ __forceinline__ void publish(float2* __restrict__ b, int fq,
                                        const float (&R)[NTRI], const float (&I)[NTRI]) {
#pragma unroll
  for (int e = 0; e < NTRI; ++e) b[e*128 + fq] = make_float2(R[e], I[e]);
}

// v <- G v  (9x9 lower-triangular complex, in-place descending L)
__device__ __forceinline__ void matvec(const float (&GR)[NTRI], const float (&GI)[NTRI],
                                       float (&vr)[9], float (&vi)[9]) {
#pragma unroll
  for (int L = 8; L >= 0; --L) {
    float sr = 0.f, si = 0.f;
#pragma unroll
    for (int q = 0; q <= L; ++q) {
      float xr = vr[q], xi = vi[q];
      sr += GR[TRI(L,q)]*xr - GI[TRI(L,q)]*xi;
      si += GR[TRI(L,q)]*xi + GI[TRI(L,q)]*xr;
    }
    vr[L] = sr; vi[L] = si;
  }
}

// Acc <- B * Acc with B streamed from LDS row-by-row (keeps live regs ~130:
// A=90, B-row<=18, temps<=18 -> no spills at the compiler's 128-VGPR target)
__device__ __forceinline__ void matmulL(const float2* __restrict__ b, int fq,
                                        float (&Ar)[NTRI], float (&Ai)[NTRI]) {
#pragma unroll
  for (int L = 8; L >= 0; --L) {
    float Br_[9], Bi_[9];
#pragma unroll
    for (int r = 0; r <= L; ++r) {
      float2 t = b[TRI(L,r)*128 + fq];
      Br_[r] = t.x; Bi_[r] = t.y;
    }
    float tr[9], ti[9];
#pragma unroll
    for (int q = 0; q <= L; ++q) {
      float sr = 0.f, si = 0.f;
#pragma unroll
      for (int r = q; r <= L; ++r) {
        float ar = Ar[TRI(r,q)], ai = Ai[TRI(r,q)];
        sr += Br_[r]*ar - Bi_[r]*ai;
        si += Br_[r]*ai + Bi_[r]*ar;
      }
      tr[q] = sr; ti[q] = si;
    }
#pragma unroll
    for (int q = 0; q <= L; ++q) { Ar[TRI(L,q)] = tr[q]; Ai[TRI(L,q)] = ti[q]; }
  }
}

// ----------------------------------------------------- setup (phat + ab) ---
__global__ __launch_bounds__(128)
void sk_setup(const int* __restrict__ seq,
              const float* __restrict__ hw,    // [8][128][4]
              const float* __restrict__ sw,    // [8][4]
              float2* __restrict__ phat,       // out [4][8][128]
              float2* __restrict__ ab)         // out [8192][8]
{
  const int tid = threadIdx.x;
  const int bid = blockIdx.x;

  if (bid < 32) {
    __shared__ float probs[128];
    __shared__ float ct[128], st[128];
    __shared__ float red[4];
    const int r = bid, p = r >> 2, c = r & 3;
    const int wave = tid >> 6, lane = tid & 63;

    float h = hw[p*512 + tid*4 + c];
    float mx = h;
    #pragma unroll
    for (int off = 1; off < 64; off <<= 1) mx = fmaxf(mx, __shfl_xor(mx, off));
    if (lane == 0) red[wave] = mx;
    __syncthreads();
    mx = fmaxf(red[0], red[1]);
    float e = expf(h - mx);
    float s = e;
    #pragma unroll
    for (int off = 1; off < 64; off <<= 1) s += __shfl_xor(s, off);
    if (lane == 0) red[2 + wave] = s;
    float th = 6.28318530717958647692f * (float)tid / 128.0f;
    ct[tid] = cosf(th); st[tid] = sinf(th);
    __syncthreads();
    s = red[2] + red[3];
    probs[tid] = e / s;
    __syncthreads();

    float ar = 0.f, ai = 0.f;
    for (int j = 0; j < 128; ++j) {
      float pv = probs[j];
      int w = (j * tid) & 127;
      ar += pv * ct[w];
      ai -= pv * st[w];
    }
    phat[(c*8 + p)*128 + tid] = make_float2(ar, ai);
  } else {
    const int total = NSEQ * 8;
    for (int n = (bid - 32)*128 + tid; n < total; n += 64*128) {
      const int i = n >> 3, Lm1 = n & 7, L = Lm1 + 1;
      int cc0 = seq[i];
      bool valid = (cc0 >= 0) && (cc0 < 4);
      int cc = min(max(cc0, 0), 3);
      bool gate = valid && (L <= i + 1);
      float z  = (float)L / (float)(i + 1);
      float sg = 1.0f / (1.0f + expf(-sw[Lm1*4 + cc]));
      float a = gate ? (1.0f - z) : 1.0f;
      float b = gate ? (z * sg) : 0.0f;
      ab[n] = make_float2(a, b);
    }
  }
}

// ------------------------------------------- 64-step segment matrices -----
// 128 blocks x 512 threads: unit u = tid>>7 builds a 16-step matrix in regs,
// then 2-level in-block tree (B streamed from LDS) -> one matrix per block.
__global__ __launch_bounds__(512)
void sk_seg(const int* __restrict__ seq,
            const float2* __restrict__ phat_g,
            const float2* __restrict__ ab_g,
            float2* __restrict__ mseg)
{
  __shared__ float2 phS[4096];          // 32 KB  [c][p][k]
  __shared__ float2 abS[SEG*8];         // 4 KB
  __shared__ int    chS[SEG];
  __shared__ float2 tb[2][NTRI*128];    // 92 KB tree buffers
  const int tid = threadIdx.x;
  const int u   = tid >> 7, fq = tid & 127;
  const int m   = blockIdx.x;

  {
    const float4* src = (const float4*)phat_g;
    float4* dst = (float4*)phS;
    for (int i = tid; i < 2048; i += 512) dst[i] = src[i];
  }
  for (int i = tid; i < SEG*8; i += 512) abS[i] = ab_g[m*SEG*8 + i];
  if (tid < SEG) chS[tid] = seq[m*SEG + tid];
  __syncthreads();

  float Mr[NTRI], Mi[NTRI];
  #pragma unroll
  for (int e = 0; e < NTRI; ++e) { Mr[e] = 0.f; Mi[e] = 0.f; }
  #pragma unroll
  for (int L = 0; L <= 8; ++L) Mr[TRI(L,L)] = 1.0f;

  const int t0 = u * SUB;
  for (int t = 0; t < SUB; ++t) {
    const int ts = t0 + t;
    const int c  = chS[ts];
    // row_L <- a*row_L + b*Phat[L-1]*row_{L-1}, in-place descending L
    #pragma unroll
    for (int L = 8; L >= 1; --L) {
      float2 abv = abS[ts*8 + (L-1)];
      float2 Pv  = phS[(c*8 + (L-1))*128 + fq];
      const float a = abv.x;
      const float bPr = abv.y * Pv.x, bPi = abv.y * Pv.y;
      #pragma unroll
      for (int q = 0; q < L; ++q) {
        float xr = Mr[TRI(L-1,q)], xi = Mi[TRI(L-1,q)];
        Mr[TRI(L,q)] = a*Mr[TRI(L,q)] + (bPr*xr - bPi*xi);
        Mi[TRI(L,q)] = a*Mi[TRI(L,q)] + (bPr*xi + bPi*xr);
      }
      Mr[TRI(L,L)] *= a;
      Mi[TRI(L,L)] *= a;
    }
  }

  // tree stage 1: units 1,3 publish; units 0,2 left-multiply from LDS
  if (u == 1 || u == 3) publish(tb[u >> 1], fq, Mr, Mi);
  __syncthreads();
  if (u == 0 || u == 2) matmulL(tb[u >> 1], fq, Mr, Mi);
  __syncthreads();
  // tree stage 2: unit 2 publishes P23; unit 0 forms P23*P01 and stores
  if (u == 2) publish(tb[1], fq, Mr, Mi);
  __syncthreads();
  if (u == 0) {
    matmulL(tb[1], fq, Mr, Mi);
    #pragma unroll
    for (int e = 0; e < NTRI; ++e)
      mseg[((size_t)m*NTRI + e)*128 + fq] = make_float2(Mr[e], Mi[e]);
  }
}

// ------------------------------------------- pairwise tree: fold 4 -> 1 ---
// Block g folds in[4g..4g+3] -> out[g]. Each unit loads ONE matrix (all
// global loads parallel), then 2-level in-block LDS tree.
__global__ __launch_bounds__(512)
void sk_comb(const float2* __restrict__ min_, float2* __restrict__ mout)
{
  __shared__ float2 tb[2][NTRI*128];    // 92 KB
  const int tid = threadIdx.x;
  const int u   = tid >> 7, fq = tid & 127;
  const int g   = blockIdx.x;

  float Ar[NTRI], Ai[NTRI];
  loadG(min_ + (size_t)(g*4 + u) * NTRI * 128, fq, Ar, Ai);

  if (u == 1 || u == 3) publish(tb[u >> 1], fq, Ar, Ai);
  __syncthreads();
  if (u == 0 || u == 2) matmulL(tb[u >> 1], fq, Ar, Ai);
  __syncthreads();
  if (u == 2) publish(tb[1], fq, Ar, Ai);
  __syncthreads();
  if (u == 0) {
    matmulL(tb[1], fq, Ar, Ai);
    #pragma unroll
    for (int e = 0; e < NTRI; ++e)
      mout[((size_t)g*NTRI + e)*128 + fq] = make_float2(Ar[e], Ai[e]);
  }
}

// --------------------- final: 8-matrix mat-vec relay + inverse DFT --------
// 1 block x 1024 threads, 8 units. Unit u loads matrix u (parallel loads),
// then an 8-hop LDS relay of v = (prod M) e0; U_k = v[8]; iDFT; write.
__global__ __launch_bounds__(1024)
void sk_fin(const float2* __restrict__ mg, float* __restrict__ out)
{
  __shared__ float2 vS[9*128];
  __shared__ float Ur[128], Ui[128];
  __shared__ float ct[128], st[128];
  const int tid = threadIdx.x;
  const int u   = tid >> 7, fq = tid & 127;

  float Ar[NTRI], Ai[NTRI];
  loadG(mg + (size_t)u * NTRI * 128, fq, Ar, Ai);

  if (tid < 128) {
    float th = 6.28318530717958647692f * (float)tid / 128.0f;
    ct[tid] = cosf(th); st[tid] = sinf(th);
  }

  float vr[9], vi[9];
  if (u == 0) {
    // v = M0 * e0 = column 0 of M0
    #pragma unroll
    for (int L = 0; L <= 8; ++L) { vr[L] = Ar[TRI(L,0)]; vi[L] = Ai[TRI(L,0)]; }
    #pragma unroll
    for (int L = 0; L <= 8; ++L) vS[L*128 + fq] = make_float2(vr[L], vi[L]);
  }
  __syncthreads();
  for (int uu = 1; uu < 8; ++uu) {
    if (u == uu) {
      #pragma unroll
      for (int L = 0; L <= 8; ++L) { float2 t = vS[L*128 + fq]; vr[L] = t.x; vi[L] = t.y; }
      matvec(Ar, Ai, vr, vi);
      #pragma unroll
      for (int L = 0; L <= 8; ++L) vS[L*128 + fq] = make_float2(vr[L], vi[L]);
    }
    __syncthreads();
  }

  if (tid < 128) {
    float2 uv = vS[8*128 + tid];
    Ur[tid] = uv.x; Ui[tid] = uv.y;
  }
  __syncthreads();

  if (tid < 128) {
    // out[j] = (1/128) sum_k Re(U_k e^{+2pi i jk/128})
    float acc = 0.f;
    for (int k = 0; k < 128; ++k) {
      int w = (tid * k) & 127;
      acc += Ur[k]*ct[w] - Ui[k]*st[w];
    }
    out[tid] = acc * (1.0f/128.0f);
  }
}

// ---------------------------------------------------------------- launch ---
extern "C" void kernel_launch(void* const* d_in, const int* in_sizes, int n_in,
                              void* d_out, int out_size, void* d_ws, size_t ws_size,
                              hipStream_t stream)
{
  const int*   seq = (const int*)d_in[0];
  const float* hw  = (const float*)d_in[1];
  const float* sw  = (const float*)d_in[2];

  char* base = (char*)d_ws;
  float2* phat = (float2*)(base + OFF_PHAT);
  float2* ab   = (float2*)(base + OFF_AB);
  float2* mseg = (float2*)(base + OFF_MSEG);
  float2* mt1  = (float2*)(base + OFF_MT1);
  float2* mt2  = (float2*)(base + OFF_MT2);

  sk_setup<<<96, 128, 0, stream>>>(seq, hw, sw, phat, ab);
  sk_seg<<<NSEGB, 512, 0, stream>>>(seq, phat, ab, mseg);
  sk_comb<<<32, 512, 0, stream>>>(mseg, mt1);   // 128 -> 32
  sk_comb<<<8, 512, 0, stream>>>(mt1, mt2);     //  32 -> 8
  sk_fin<<<1, 1024, 0, stream>>>(mt2, (float*)d_out);
}

// Round 6
// 124.043 us; speedup vs baseline: 1.4686x; 1.4686x over previous
//
#include <hip/hip_runtime.h>
#include <math.h>

#define DDIM 128
#define NSEQ 8192
#define SUB 16        // steps per unit in sk_seg
#define SEG 64        // steps per seg block (4 units)
#define NSEGB 128     // 8192/64 -> 128 segment matrices
#define NTRI 45       // lower-triangular entries (L,q), q<=L, L=0..8

#define TRI(L,q) ((L)*((L)+1)/2 + (q))

// ws layout (bytes)
#define OFF_PHAT 0                      // float2 [4][8][128]    = 32768
#define OFF_AB   32768                  // float2 [8192][8]      = 524288
#define OFF_MSEG 557056                 // float2 [128][45][128] = 5898240
#define OFF_MT1  6455296                // float2 [32][45][128]  = 1474560
#define OFF_MT2  7929856                // float2 [8][45][128]   = 368640
// total ~8.3 MB

// ---------------------------------------------------------- reg helpers ----
__device__ __forceinline__ void loadG(const float2* __restrict__ p, int fq,
                                      float (&R)[NTRI], float (&I)[NTRI]) {
#pragma unroll
  for (int e = 0; e < NTRI; ++e) {
    float2 t = p[e*128 + fq];
    R[e] = t.x; I[e] = t.y;
  }
}

__device__ __forceinline__ void publish(float2* __restrict__ b, int fq,
                                        const float (&R)[NTRI], const float (&I)[NTRI]) {
#pragma unroll
  for (int e = 0; e < NTRI; ++e) b[e*128 + fq] = make_float2(R[e], I[e]);
}

// v <- G v  (9x9 lower-triangular complex, in-place descending L)
__device__ __forceinline__ void matvec(const float (&GR)[NTRI], const float (&GI)[NTRI],
                                       float (&vr)[9], float (&vi)[9]) {
#pragma unroll
  for (int L = 8; L >= 0; --L) {
    float sr = 0.f, si = 0.f;
#pragma unroll
    for (int q = 0; q <= L; ++q) {
      float xr = vr[q], xi = vi[q];
      sr += GR[TRI(L,q)]*xr - GI[TRI(L,q)]*xi;
      si += GR[TRI(L,q)]*xi + GI[TRI(L,q)]*xr;
    }
    vr[L] = sr; vi[L] = si;
  }
}

// Acc <- B * Acc with B streamed from LDS row-by-row (keeps live regs ~130:
// A=90, B-row<=18, temps<=18 -> no spill at the compiler's 128-VGPR target)
__device__ __forceinline__ void matmulL(const float2* __restrict__ b, int fq,
                                        float (&Ar)[NTRI], float (&Ai)[NTRI]) {
#pragma unroll
  for (int L = 8; L >= 0; --L) {
    float Br_[9], Bi_[9];
#pragma unroll
    for (int r = 0; r <= L; ++r) {
      float2 t = b[TRI(L,r)*128 + fq];
      Br_[r] = t.x; Bi_[r] = t.y;
    }
    float tr[9], ti[9];
#pragma unroll
    for (int q = 0; q <= L; ++q) {
      float sr = 0.f, si = 0.f;
#pragma unroll
      for (int r = q; r <= L; ++r) {
        float ar = Ar[TRI(r,q)], ai = Ai[TRI(r,q)];
        sr += Br_[r]*ar - Bi_[r]*ai;
        si += Br_[r]*ai + Bi_[r]*ar;
      }
      tr[q] = sr; ti[q] = si;
    }
#pragma unroll
    for (int q = 0; q <= L; ++q) { Ar[TRI(L,q)] = tr[q]; Ai[TRI(L,q)] = ti[q]; }
  }
}

// ----------------------------------------------------- setup (phat + ab) ---
__global__ __launch_bounds__(128)
void sk_setup(const int* __restrict__ seq,
              const float* __restrict__ hw,    // [8][128][4]
              const float* __restrict__ sw,    // [8][4]
              float2* __restrict__ phat,       // out [4][8][128]
              float2* __restrict__ ab)         // out [8192][8]
{
  const int tid = threadIdx.x;
  const int bid = blockIdx.x;

  if (bid < 32) {
    __shared__ float probs[128];
    __shared__ float ct[128], st[128];
    __shared__ float red[4];
    const int r = bid, p = r >> 2, c = r & 3;
    const int wave = tid >> 6, lane = tid & 63;

    float h = hw[p*512 + tid*4 + c];
    float mx = h;
    #pragma unroll
    for (int off = 1; off < 64; off <<= 1) mx = fmaxf(mx, __shfl_xor(mx, off));
    if (lane == 0) red[wave] = mx;
    __syncthreads();
    mx = fmaxf(red[0], red[1]);
    float e = expf(h - mx);
    float s = e;
    #pragma unroll
    for (int off = 1; off < 64; off <<= 1) s += __shfl_xor(s, off);
    if (lane == 0) red[2 + wave] = s;
    float th = 6.28318530717958647692f * (float)tid / 128.0f;
    ct[tid] = cosf(th); st[tid] = sinf(th);
    __syncthreads();
    s = red[2] + red[3];
    probs[tid] = e / s;
    __syncthreads();

    float ar = 0.f, ai = 0.f;
    for (int j = 0; j < 128; ++j) {
      float pv = probs[j];
      int w = (j * tid) & 127;
      ar += pv * ct[w];
      ai -= pv * st[w];
    }
    phat[(c*8 + p)*128 + tid] = make_float2(ar, ai);
  } else {
    const int total = NSEQ * 8;
    for (int n = (bid - 32)*128 + tid; n < total; n += 64*128) {
      const int i = n >> 3, Lm1 = n & 7, L = Lm1 + 1;
      int cc0 = seq[i];
      bool valid = (cc0 >= 0) && (cc0 < 4);
      int cc = min(max(cc0, 0), 3);
      bool gate = valid && (L <= i + 1);
      float z  = (float)L / (float)(i + 1);
      float sg = 1.0f / (1.0f + expf(-sw[Lm1*4 + cc]));
      float a = gate ? (1.0f - z) : 1.0f;
      float b = gate ? (z * sg) : 0.0f;
      ab[n] = make_float2(a, b);
    }
  }
}

// ------------------------------------------- 64-step segment matrices -----
// 128 blocks x 512 threads: unit u = tid>>7 builds a 16-step matrix in regs,
// then 2-level in-block tree (B streamed from LDS) -> one matrix per block.
__global__ __launch_bounds__(512)
void sk_seg(const int* __restrict__ seq,
            const float2* __restrict__ phat_g,
            const float2* __restrict__ ab_g,
            float2* __restrict__ mseg)
{
  __shared__ float2 phS[4096];          // 32 KB  [c][p][k]
  __shared__ float2 abS[SEG*8];         // 4 KB
  __shared__ int    chS[SEG];
  __shared__ float2 tb[2][NTRI*128];    // 92 KB tree buffers
  const int tid = threadIdx.x;
  const int u   = tid >> 7, fq = tid & 127;
  const int m   = blockIdx.x;

  {
    const float4* src = (const float4*)phat_g;
    float4* dst = (float4*)phS;
    for (int i = tid; i < 2048; i += 512) dst[i] = src[i];
  }
  for (int i = tid; i < SEG*8; i += 512) abS[i] = ab_g[m*SEG*8 + i];
  if (tid < SEG) chS[tid] = seq[m*SEG + tid];
  __syncthreads();

  float Mr[NTRI], Mi[NTRI];
  #pragma unroll
  for (int e = 0; e < NTRI; ++e) { Mr[e] = 0.f; Mi[e] = 0.f; }
  #pragma unroll
  for (int L = 0; L <= 8; ++L) Mr[TRI(L,L)] = 1.0f;

  const int t0 = u * SUB;
  for (int t = 0; t < SUB; ++t) {
    const int ts = t0 + t;
    const int c  = chS[ts];
    // row_L <- a*row_L + b*Phat[L-1]*row_{L-1}, in-place descending L
    #pragma unroll
    for (int L = 8; L >= 1; --L) {
      float2 abv = abS[ts*8 + (L-1)];
      float2 Pv  = phS[(c*8 + (L-1))*128 + fq];
      const float a = abv.x;
      const float bPr = abv.y * Pv.x, bPi = abv.y * Pv.y;
      #pragma unroll
      for (int q = 0; q < L; ++q) {
        float xr = Mr[TRI(L-1,q)], xi = Mi[TRI(L-1,q)];
        Mr[TRI(L,q)] = a*Mr[TRI(L,q)] + (bPr*xr - bPi*xi);
        Mi[TRI(L,q)] = a*Mi[TRI(L,q)] + (bPr*xi + bPi*xr);
      }
      Mr[TRI(L,L)] *= a;
      Mi[TRI(L,L)] *= a;
    }
  }

  // tree stage 1: units 1,3 publish; units 0,2 left-multiply from LDS
  if (u == 1 || u == 3) publish(tb[u >> 1], fq, Mr, Mi);
  __syncthreads();
  if (u == 0 || u == 2) matmulL(tb[u >> 1], fq, Mr, Mi);
  __syncthreads();
  // tree stage 2: unit 2 publishes P23; unit 0 forms P23*P01 and stores
  if (u == 2) publish(tb[1], fq, Mr, Mi);
  __syncthreads();
  if (u == 0) {
    matmulL(tb[1], fq, Mr, Mi);
    #pragma unroll
    for (int e = 0; e < NTRI; ++e)
      mseg[((size_t)m*NTRI + e)*128 + fq] = make_float2(Mr[e], Mi[e]);
  }
}

// ------------------------------------------- pairwise tree: fold 4 -> 1 ---
// Block g folds in[4g..4g+3] -> out[g]. Each unit loads ONE matrix (all
// global loads parallel), then 2-level in-block LDS tree.
__global__ __launch_bounds__(512)
void sk_comb(const float2* __restrict__ min_, float2* __restrict__ mout)
{
  __shared__ float2 tb[2][NTRI*128];    // 92 KB
  const int tid = threadIdx.x;
  const int u   = tid >> 7, fq = tid & 127;
  const int g   = blockIdx.x;

  float Ar[NTRI], Ai[NTRI];
  loadG(min_ + (size_t)(g*4 + u) * NTRI * 128, fq, Ar, Ai);

  if (u == 1 || u == 3) publish(tb[u >> 1], fq, Ar, Ai);
  __syncthreads();
  if (u == 0 || u == 2) matmulL(tb[u >> 1], fq, Ar, Ai);
  __syncthreads();
  if (u == 2) publish(tb[1], fq, Ar, Ai);
  __syncthreads();
  if (u == 0) {
    matmulL(tb[1], fq, Ar, Ai);
    #pragma unroll
    for (int e = 0; e < NTRI; ++e)
      mout[((size_t)g*NTRI + e)*128 + fq] = make_float2(Ar[e], Ai[e]);
  }
}

// ---------------- final: fold 8 matrices (two tree passes) + iDFT ---------
// 1 block x 512 threads (4 units; same proven shape as sk_comb, no spills).
// Only the e0-image is needed: v = P_hi * (P_lo * e0); U_k = v[8]; iDFT.
__global__ __launch_bounds__(512)
void sk_fin8(const float2* __restrict__ mg, float* __restrict__ out)
{
  __shared__ float2 tb[2][NTRI*128];    // 92 KB tree buffers (reused)
  __shared__ float2 vS[9*128];          // P_lo * e0
  __shared__ float Ur[128], Ui[128], ct[128], st[128];
  const int tid = threadIdx.x;
  const int u   = tid >> 7, fq = tid & 127;

  float Ar[NTRI], Ai[NTRI];
  loadG(mg + (size_t)u * NTRI * 128, fq, Ar, Ai);   // M0..M3

  if (tid < 128) {
    float th = 6.28318530717958647692f * (float)tid / 128.0f;
    ct[tid] = cosf(th); st[tid] = sinf(th);
  }

  // ---- tree fold low half: P_lo = M3*M2*M1*M0 ----
  if (u == 1 || u == 3) publish(tb[u >> 1], fq, Ar, Ai);
  __syncthreads();
  if (u == 0 || u == 2) matmulL(tb[u >> 1], fq, Ar, Ai);
  __syncthreads();
  if (u == 2) publish(tb[1], fq, Ar, Ai);
  __syncthreads();
  if (u == 0) {
    matmulL(tb[1], fq, Ar, Ai);                     // P_lo in u0 regs
    #pragma unroll
    for (int L = 0; L <= 8; ++L)                    // publish P_lo * e0 (col 0)
      vS[L*128 + fq] = make_float2(Ar[TRI(L,0)], Ai[TRI(L,0)]);
  }
  __syncthreads();                                  // vS ready; tb reusable

  // ---- tree fold high half: P_hi = M7*M6*M5*M4 ----
  loadG(mg + (size_t)(4 + u) * NTRI * 128, fq, Ar, Ai);
  if (u == 1 || u == 3) publish(tb[u >> 1], fq, Ar, Ai);
  __syncthreads();
  if (u == 0 || u == 2) matmulL(tb[u >> 1], fq, Ar, Ai);
  __syncthreads();
  if (u == 2) publish(tb[1], fq, Ar, Ai);
  __syncthreads();
  if (u == 0) {
    matmulL(tb[1], fq, Ar, Ai);                     // P_hi in u0 regs
    float vr[9], vi[9];
    #pragma unroll
    for (int L = 0; L <= 8; ++L) { float2 t = vS[L*128 + fq]; vr[L] = t.x; vi[L] = t.y; }
    matvec(Ar, Ai, vr, vi);                         // v = P_hi * (P_lo e0)
    Ur[fq] = vr[8]; Ui[fq] = vi[8];
  }
  __syncthreads();

  if (tid < 128) {
    // out[j] = (1/128) sum_k Re(U_k e^{+2pi i jk/128})
    float acc = 0.f;
    for (int k = 0; k < 128; ++k) {
      int w = (tid * k) & 127;
      acc += Ur[k]*ct[w] - Ui[k]*st[w];
    }
    out[tid] = acc * (1.0f/128.0f);
  }
}

// ---------------------------------------------------------------- launch ---
extern "C" void kernel_launch(void* const* d_in, const int* in_sizes, int n_in,
                              void* d_out, int out_size, void* d_ws, size_t ws_size,
                              hipStream_t stream)
{
  const int*   seq = (const int*)d_in[0];
  const float* hw  = (const float*)d_in[1];
  const float* sw  = (const float*)d_in[2];

  char* base = (char*)d_ws;
  float2* phat = (float2*)(base + OFF_PHAT);
  float2* ab   = (float2*)(base + OFF_AB);
  float2* mseg = (float2*)(base + OFF_MSEG);
  float2* mt1  = (float2*)(base + OFF_MT1);
  float2* mt2  = (float2*)(base + OFF_MT2);

  sk_setup<<<96, 128, 0, stream>>>(seq, hw, sw, phat, ab);
  sk_seg<<<NSEGB, 512, 0, stream>>>(seq, phat, ab, mseg);
  sk_comb<<<32, 512, 0, stream>>>(mseg, mt1);   // 128 -> 32
  sk_comb<<<8, 512, 0, stream>>>(mt1, mt2);     //  32 -> 8
  sk_fin8<<<1, 512, 0, stream>>>(mt2, (float*)d_out);
}